// Round 16
// baseline (39.898 us; speedup 1.0000x reference)
//
#include <hip/hip_runtime.h>
#include <hip/hip_bf16.h>

#define B_ 8
#define T_ 2048
#define V_ 256
#define D_ 512
#define LEFT_ 16

typedef float f32x4 __attribute__((ext_vector_type(4)));
typedef short bf16x8 __attribute__((ext_vector_type(8)));
union FragU { unsigned u[4]; bf16x8 v; };

__device__ __forceinline__ unsigned pack_bf2(float a, float b) {
    __hip_bfloat162 h = __float22bfloat162_rn(make_float2(a, b));
    union { __hip_bfloat162 h; unsigned u; } c; c.h = h; return c.u;
}

// ---- kernel A: scores + softmax -> p ; fused exact-f32 enc passthrough ----
// Block = 16 tokens, 8 waves, one barrier (R15 phase-A structure, phase B removed).
__global__ __launch_bounds__(512)
void score_kernel(const int* __restrict__ symbols,
                  const float* __restrict__ encodings,
                  const float* __restrict__ M,
                  float* __restrict__ out,      // (B,T,1024)
                  float* __restrict__ p_out) {  // (B,T,16)
    __shared__ __align__(16) float sp[8 * 16 * 36];            // 18432 B

    const int tid  = threadIdx.x;
    const int lane = tid & 63;
    const int w    = tid >> 6;
    const int q    = lane >> 4;
    const int t    = lane & 15;

    const int blk = blockIdx.x;
    const int b   = blk >> 7;
    const int t0  = (blk & 127) * 16;
    const int* symrow = symbols + b * T_;
    const size_t rowbase = (size_t)b * T_ + t0;

    int sa[2];
    #pragma unroll
    for (int g = 0; g < 2; ++g) {
        int pos = t0 + t + 16 * g - (LEFT_ - 1);
        pos = max(pos, 0); pos = min(pos, T_ - 1);
        sa[g] = symrow[pos];
    }

    FragU bf[2];
    {
        const float* ebase = encodings + (rowbase + t) * D_;
        float* obase = out + (rowbase + t) * 1024 + D_;
        #pragma unroll
        for (int kc = 0; kc < 2; ++kc) {
            const int d0 = 64 * w + 32 * kc + 4 * q;
            const float4 e0 = *(const float4*)(ebase + d0);
            const float4 e1 = *(const float4*)(ebase + d0 + 16);
            *(float4*)(obase + d0)      = e0;   // exact f32 enc passthrough
            *(float4*)(obase + d0 + 16) = e1;
            bf[kc].u[0] = pack_bf2(e0.x, e0.y); bf[kc].u[1] = pack_bf2(e0.z, e0.w);
            bf[kc].u[2] = pack_bf2(e1.x, e1.y); bf[kc].u[3] = pack_bf2(e1.z, e1.w);
        }
    }

    f32x4 acc0 = {0.f, 0.f, 0.f, 0.f}, acc1 = {0.f, 0.f, 0.f, 0.f};
    #pragma unroll
    for (int kc = 0; kc < 2; ++kc) {
        const int k0 = 64 * w + 32 * kc + 4 * q;
        {
            const float* ma = M + (size_t)sa[0] * D_ + k0;
            const float4 x0 = *(const float4*)ma;
            const float4 x1 = *(const float4*)(ma + 16);
            FragU af;
            af.u[0] = pack_bf2(x0.x, x0.y); af.u[1] = pack_bf2(x0.z, x0.w);
            af.u[2] = pack_bf2(x1.x, x1.y); af.u[3] = pack_bf2(x1.z, x1.w);
            acc0 = __builtin_amdgcn_mfma_f32_16x16x32_bf16(af.v, bf[kc].v, acc0, 0, 0, 0);
        }
        {
            const float* ma = M + (size_t)sa[1] * D_ + k0;
            const float4 x0 = *(const float4*)ma;
            const float4 x1 = *(const float4*)(ma + 16);
            FragU af;
            af.u[0] = pack_bf2(x0.x, x0.y); af.u[1] = pack_bf2(x0.z, x0.w);
            af.u[2] = pack_bf2(x1.x, x1.y); af.u[3] = pack_bf2(x1.z, x1.w);
            acc1 = __builtin_amdgcn_mfma_f32_16x16x32_bf16(af.v, bf[kc].v, acc1, 0, 0, 0);
        }
    }
    *(f32x4*)&sp[(w * 16 + t) * 36 + 4 * q]      = acc0;
    *(f32x4*)&sp[(w * 16 + t) * 36 + 16 + 4 * q] = acc1;

    __syncthreads();

    // reduce 8 slices; masked band softmax; p store (R10-15-verified layout)
    {
        f32x4 s0 = *(const f32x4*)&sp[t * 36 + 4 * q];
        f32x4 s1 = *(const f32x4*)&sp[t * 36 + 16 + 4 * q];
        #pragma unroll
        for (int w2 = 1; w2 < 8; ++w2) {
            s0 += *(const f32x4*)&sp[(w2 * 16 + t) * 36 + 4 * q];
            s1 += *(const f32x4*)&sp[(w2 * 16 + t) * 36 + 16 + 4 * q];
        }
        float mx = -3.0e38f;
        #pragma unroll
        for (int r = 0; r < 4; ++r) {
            if ((unsigned)(4 * q + r - t) < 16u)      mx = fmaxf(mx, s0[r]);
            if ((unsigned)(4 * q + r + 16 - t) < 16u) mx = fmaxf(mx, s1[r]);
        }
        mx = fmaxf(mx, __shfl_xor(mx, 16));
        mx = fmaxf(mx, __shfl_xor(mx, 32));
        float p0[4], p1[4];
        float sum = 0.f;
        #pragma unroll
        for (int r = 0; r < 4; ++r) {
            const bool m0 = (unsigned)(4 * q + r - t) < 16u;
            const bool m1 = (unsigned)(4 * q + r + 16 - t) < 16u;
            p0[r] = m0 ? __expf(s0[r] - mx) : 0.f;
            p1[r] = m1 ? __expf(s1[r] - mx) : 0.f;
            sum += p0[r] + p1[r];
        }
        sum += __shfl_xor(sum, 16);
        sum += __shfl_xor(sum, 32);
        const float inv = 1.f / sum;

        if (w == 0) {
            #pragma unroll
            for (int r = 0; r < 4; ++r) {
                const int j0 = 4 * q + r;
                if ((unsigned)(j0 - t) < 16u)
                    p_out[(rowbase + t) * 16 + (j0 - t)] = p0[r] * inv;
                else
                    p_out[(rowbase + t) * 16 + (j0 + 16 - t)] = p1[r] * inv;
            }
        }
    }
}

// ---- kernel B: compressed = sum_j p[t][j] * C[sym] ; wave-autonomous, no LDS ----
__global__ __launch_bounds__(256)
void compress_kernel(const int* __restrict__ symbols,
                     const float* __restrict__ C,
                     const float* __restrict__ p_in,   // (B,T,16), written by A
                     float* __restrict__ out) {        // (B,T,1024)
    const int tid  = threadIdx.x;
    const int lane = tid & 63;
    const int w    = tid >> 6;

    const int blk = blockIdx.x;
    const int b   = blk >> 7;                      // 128 blocks per batch row
    const int tb  = (blk & 127) * 16 + w * 4;      // wave's first token
    const int* symrow = symbols + b * T_;
    const size_t rowbase = (size_t)b * T_ + tb;
    const int dof = lane * 8;

    // p for the wave's 4 tokens: lane (l&15) holds slot l&15
    float pv[4];
    #pragma unroll
    for (int tk = 0; tk < 4; ++tk)
        pv[tk] = p_in[(rowbase + tk) * 16 + (lane & 15)];

    float4 a0[4], a1[4];
    #pragma unroll
    for (int tk = 0; tk < 4; ++tk) {
        a0[tk] = make_float4(0.f, 0.f, 0.f, 0.f);
        a1[tk] = make_float4(0.f, 0.f, 0.f, 0.f);
    }

    #pragma unroll
    for (int i = 0; i < 19; ++i) {                 // window rows tb-15 .. tb+3
        int pos = tb - (LEFT_ - 1) + i;
        pos = max(pos, 0);
        const int sym = __builtin_amdgcn_readfirstlane(symrow[pos]);
        const float* cr = C + (size_t)sym * D_ + dof;
        const float4 c0 = *(const float4*)cr;
        const float4 c1 = *(const float4*)(cr + 4);
        #pragma unroll
        for (int tk = 0; tk < 4; ++tk) {
            const int sl = i - tk;
            if (sl >= 0 && sl < 16) {
                const float pb = __shfl(pv[tk], sl);
                a0[tk].x += pb * c0.x; a0[tk].y += pb * c0.y;
                a0[tk].z += pb * c0.z; a0[tk].w += pb * c0.w;
                a1[tk].x += pb * c1.x; a1[tk].y += pb * c1.y;
                a1[tk].z += pb * c1.z; a1[tk].w += pb * c1.w;
            }
        }
    }

    #pragma unroll
    for (int tk = 0; tk < 4; ++tk) {
        float* ob = out + (rowbase + tk) * 1024 + dof;
        *(float4*)ob       = a0[tk];
        *(float4*)(ob + 4) = a1[tk];
    }
}

extern "C" void kernel_launch(void* const* d_in, const int* in_sizes, int n_in,
                              void* d_out, int out_size, void* d_ws, size_t ws_size,
                              hipStream_t stream) {
    const int*   symbols   = (const int*)d_in[0];
    const float* encodings = (const float*)d_in[1];
    const float* M         = (const float*)d_in[2];
    const float* C         = (const float*)d_in[3];
    float* out   = (float*)d_out;
    float* p_out = out + (size_t)B_ * T_ * 1024;   // concat order: output, then p

    dim3 grid(B_ * (T_ / 16));                     // 1024 blocks
    score_kernel<<<grid, 512, 0, stream>>>(symbols, encodings, M, out, p_out);
    compress_kernel<<<grid, 256, 0, stream>>>(symbols, C, p_out, out);
}